// Round 12
// baseline (147.226 us; speedup 1.0000x reference)
//
#include <hip/hip_runtime.h>

// Problem constants (from reference setup_inputs)
#define BATCH 16
#define CIN   3
#define H     384
#define W     384
#define HW    (H * W)
#define HO    382
#define WO    382
#define OFFC  18
#define OOUT  3
#define KTAPS 9

// Padded frame: 2-px zero halo reproduces OOB-mask semantics.
#define PAD   2
#define HP    (H + 2 * PAD)     // 388
#define WP    (W + 2 * PAD)     // 388

// Packed-weight region (floats):
//  [0..485]   pk_cw : k in 0..8, idx in 0..26 -> {cw[2k][idx], cw[2k+1][idx]}
//  [486..503] pk_cb : {conv_b[2k], conv_b[2k+1]}
//  [504..557] pk_dw : ck in 0..26 -> {dcn_w[0][ck], dcn_w[1][ck]}
//  [558..584] dw2   : dcn_w[2][ck]
//  [585..586] db01, [587] db2
#define WPK_FLOATS 588

typedef float vf2 __attribute__((ext_vector_type(2)));

static __device__ __forceinline__ vf2 splat2(float s) { vf2 r; r.x = s; r.y = s; return r; }

// bf16 helpers: RNE pack, cheap unpack (bf16<<16 IS the fp32).
static __device__ __forceinline__ unsigned f2bf(float f) {
    const unsigned u = __float_as_uint(f);
    return (u + 0x7fffu + ((u >> 16) & 1u)) >> 16;
}
static __device__ __forceinline__ float bf_lo(unsigned d) { return __uint_as_float(d << 16); }
static __device__ __forceinline__ float bf_hi(unsigned d) { return __uint_as_float(d & 0xffff0000u); }

// ---------------------------------------------------------------------------
// Pass 0: pack weights into pk layout (tiny; runs every call — graph-safe).
__global__ __launch_bounds__(256)
void prep_weights_kernel(const float* __restrict__ conv_w,
                         const float* __restrict__ conv_b,
                         const float* __restrict__ dcn_w,
                         const float* __restrict__ dcn_b,
                         float* __restrict__ wpk)
{
    for (int i = threadIdx.x; i < WPK_FLOATS; i += 256) {
        float v;
        if (i < 486) {
            const int k    = i / 54;
            const int r    = i - k * 54;
            const int idx  = r >> 1;
            const int half = r & 1;
            v = conv_w[(2 * k + half) * 27 + idx];
        } else if (i < 504) {
            v = conv_b[i - 486];
        } else if (i < 558) {
            const int r    = i - 504;
            const int ck   = r >> 1;
            const int half = r & 1;
            v = dcn_w[half * 27 + ck];
        } else if (i < 585) {
            v = dcn_w[2 * 27 + (i - 558)];
        } else if (i < 587) {
            v = dcn_b[i - 585];
        } else {
            v = dcn_b[2];
        }
        wpk[i] = v;
    }
}

// ---------------------------------------------------------------------------
// Pass 1: CHW fp32 -> padded PAIR-CELL bf16 buffer.
// Cell (y,x) = [px(y,x), px(y,x+1)], each px = (ch0|ch1<<16, ch2) -> uint4.
// One aligned dwordx4 load = BOTH horizontal corners of a bilinear row.
__global__ __launch_bounds__(256)
void chw_to_cells_kernel(const float* __restrict__ x, uint4* __restrict__ cells)
{
    const int gid = blockIdx.x * 256 + threadIdx.x;
    if (gid >= BATCH * HP * WP) return;
    const int b  = gid / (HP * WP);
    const int r2 = gid - b * (HP * WP);
    const int ry = r2 / WP;
    const int rx = r2 - ry * WP;
    const int yi = ry - PAD;
    const float* xb = x + (size_t)b * (CIN * HW);

    uint4 v = make_uint4(0u, 0u, 0u, 0u);
    if ((unsigned)yi < (unsigned)H) {
        const int xiA = rx - PAD;
        const int xiB = xiA + 1;
        if ((unsigned)xiA < (unsigned)W) {
            const int p = yi * W + xiA;
            v.x = f2bf(xb[p]) | (f2bf(xb[HW + p]) << 16);
            v.y = f2bf(xb[2 * HW + p]);
        }
        if ((unsigned)xiB < (unsigned)W) {
            const int p = yi * W + xiB;
            v.z = f2bf(xb[p]) | (f2bf(xb[HW + p]) << 16);
            v.w = f2bf(xb[2 * HW + p]);
        }
    }
    cells[gid] = v;
}

// ---------------------------------------------------------------------------
// Pass 2: 1 px/thread. Grid y = batch -> wave-uniform bases (SGPR addressing).
// Offset conv from ORIGINAL fp32 x (positions exact). Gathers: 2 aligned
// dwordx4 loads per tap from the pair-cell buffer. pk math throughout.
__global__ __launch_bounds__(256)
void deform_cells_kernel(const float* __restrict__ x,
                         const uint4* __restrict__ cells,
                         const float* __restrict__ wpk,
                         float* __restrict__ out)
{
    const int p = blockIdx.x * 256 + threadIdx.x;
    if (p >= HO * WO) return;
    const int b  = blockIdx.y;          // wave-uniform
    const int ho = p / WO;
    const int wo = p - ho * WO;

    const vf2*   pk_cw = (const vf2*)wpk;            // [k*27 + ck]
    const vf2*   pk_cb = (const vf2*)(wpk + 486);    // [k]
    const vf2*   pk_dw = (const vf2*)(wpk + 504);    // [c*9 + k]
    const float* dw2   = wpk + 558;                  // [c*9 + k]

    const float* xb = x     + (size_t)b * (CIN * HW);   // SGPR base
    const uint4* cb = cells + (size_t)b * (HP * WP);    // SGPR base

    // 3x3x3 fp32 patch from original CHW x (1 voffset + imm offsets).
    float xp[CIN][3][3];
    #pragma unroll
    for (int c = 0; c < CIN; ++c) {
        const float* xc = xb + c * HW + ho * W + wo;
        #pragma unroll
        for (int i = 0; i < 3; ++i)
            #pragma unroll
            for (int j = 0; j < 3; ++j)
                xp[c][i][j] = xc[i * W + j];
    }

    // Offset conv: 9 (dy,dx) pairs, 27 pk-FMA each (fp32-exact positions).
    vf2 off2[KTAPS];
    #pragma unroll
    for (int k = 0; k < KTAPS; ++k) {
        vf2 a = pk_cb[k];
        #pragma unroll
        for (int c = 0; c < CIN; ++c)
            #pragma unroll
            for (int i = 0; i < 3; ++i)
                #pragma unroll
                for (int j = 0; j < 3; ++j)
                    a = __builtin_elementwise_fma(pk_cw[k * 27 + c * 9 + i * 3 + j],
                                                  splat2(xp[c][i][j]), a);
        off2[k] = a;
    }

    vf2   acc01 = *(const vf2*)(wpk + 585);
    float acc2  = wpk[587];

    #pragma unroll
    for (int k = 0; k < KTAPS; ++k) {
        const int ky = k / 3;
        const int kx = k % 3;
        const vf2 o = off2[k];               // (dy, dx)
        vf2 f;
        f.x = floorf(o.x);
        f.y = floorf(o.y);
        const vf2 w  = o - f;                // (wy, wx)
        const vf2 cw = splat2(1.f) - w;      // (cwy, cwx)

        int iy = (int)f.x + (ho + ky + PAD);
        int ix = (int)f.y + (wo + kx + PAD);
        iy = min(max(iy, 0), HP - 2);
        ix = min(max(ix, 0), WP - 2);

        // Two aligned 16-B loads: c0 = corners (00,01), c1 = corners (10,11).
        const int ci = iy * WP + ix;
        const uint4 c0 = cb[ci];
        const uint4 c1 = cb[ci + WP];

        // Packed bilinear weights: (w00,w01) and (w10,w11) via 2 pk muls.
        vf2 wxv; wxv.x = cw.y; wxv.y = w.y;         // (cwx, wx)
        const vf2 wA = splat2(cw.x) * wxv;          // (w00, w01)
        const vf2 wB = splat2(w.x)  * wxv;          // (w10, w11)

        // Channels (0,1) packed from d0 words; channel 2 from d1 words.
        vf2 c00, c01, c10, c11;
        c00.x = bf_lo(c0.x); c00.y = bf_hi(c0.x);
        c01.x = bf_lo(c0.z); c01.y = bf_hi(c0.z);
        c10.x = bf_lo(c1.x); c10.y = bf_hi(c1.x);
        c11.x = bf_lo(c1.z); c11.y = bf_hi(c1.z);
        vf2 s01 = c00 * splat2(wA.x);
        s01 = __builtin_elementwise_fma(c01, splat2(wA.y), s01);
        s01 = __builtin_elementwise_fma(c10, splat2(wB.x), s01);
        s01 = __builtin_elementwise_fma(c11, splat2(wB.y), s01);

        float s2 = bf_lo(c0.y) * wA.x;
        s2 = fmaf(bf_lo(c0.w), wA.y, s2);
        s2 = fmaf(bf_lo(c1.y), wB.x, s2);
        s2 = fmaf(bf_lo(c1.w), wB.y, s2);

        acc01 = __builtin_elementwise_fma(pk_dw[0 * 9 + k], splat2(s01.x), acc01);
        acc01 = __builtin_elementwise_fma(pk_dw[1 * 9 + k], splat2(s01.y), acc01);
        acc01 = __builtin_elementwise_fma(pk_dw[2 * 9 + k], splat2(s2),    acc01);
        acc2 = fmaf(dw2[0 * 9 + k], s01.x, acc2);
        acc2 = fmaf(dw2[1 * 9 + k], s01.y, acc2);
        acc2 = fmaf(dw2[2 * 9 + k], s2,    acc2);
    }

    const int obase = b * (OOUT * HO * WO) + p;
    __builtin_nontemporal_store(acc01.x, out + obase);
    __builtin_nontemporal_store(acc01.y, out + obase + HO * WO);
    __builtin_nontemporal_store(acc2,    out + obase + 2 * HO * WO);
}

// ---------------------------------------------------------------------------
// Fallback A (ws >= 19.3 MB): round-11 bf16 single-px-cell path (~67 us).
__global__ __launch_bounds__(256)
void chw_to_bf16hwc_kernel(const float* __restrict__ x, uint2* __restrict__ xt)
{
    const int gid = blockIdx.x * 256 + threadIdx.x;
    if (gid >= BATCH * HP * WP) return;
    const int b  = gid / (HP * WP);
    const int r2 = gid - b * (HP * WP);
    const int ry = r2 / WP;
    const int rx = r2 - ry * WP;
    const int yi = ry - PAD;
    const int xi = rx - PAD;
    uint2 v = make_uint2(0u, 0u);
    if ((unsigned)yi < (unsigned)H && (unsigned)xi < (unsigned)W) {
        const float* xb = x + (size_t)b * (CIN * HW);
        const int p = yi * W + xi;
        v.x = f2bf(xb[p]) | (f2bf(xb[HW + p]) << 16);
        v.y = f2bf(xb[2 * HW + p]);
    }
    xt[gid] = v;
}

__global__ __launch_bounds__(256)
void deform_bf16_kernel(const float* __restrict__ x,
                        const uint2* __restrict__ xt,
                        const float* __restrict__ wpk,
                        float* __restrict__ out)
{
    const int total = BATCH * HO * WO;
    const int gid = blockIdx.x * 256 + threadIdx.x;
    if (gid >= total) return;

    const int wo  = gid % WO;
    const int tmp = gid / WO;
    const int ho  = tmp % HO;
    const int b   = tmp / HO;

    const vf2*   pk_cw = (const vf2*)wpk;
    const vf2*   pk_cb = (const vf2*)(wpk + 486);
    const vf2*   pk_dw = (const vf2*)(wpk + 504);
    const float* dw2   = wpk + 558;

    const float* xb  = x  + (size_t)b * (CIN * HW);
    const uint2* xtb = xt + (size_t)b * (HP * WP);

    float xp[CIN][3][3];
    #pragma unroll
    for (int c = 0; c < CIN; ++c) {
        const float* xc = xb + c * HW + ho * W + wo;
        #pragma unroll
        for (int i = 0; i < 3; ++i)
            #pragma unroll
            for (int j = 0; j < 3; ++j)
                xp[c][i][j] = xc[i * W + j];
    }

    vf2 off2[KTAPS];
    #pragma unroll
    for (int k = 0; k < KTAPS; ++k) {
        vf2 a = pk_cb[k];
        #pragma unroll
        for (int c = 0; c < CIN; ++c)
            #pragma unroll
            for (int i = 0; i < 3; ++i)
                #pragma unroll
                for (int j = 0; j < 3; ++j)
                    a = __builtin_elementwise_fma(pk_cw[k * 27 + c * 9 + i * 3 + j],
                                                  splat2(xp[c][i][j]), a);
        off2[k] = a;
    }

    vf2   acc01 = *(const vf2*)(wpk + 585);
    float acc2  = wpk[587];

    #pragma unroll
    for (int k = 0; k < KTAPS; ++k) {
        const int ky = k / 3;
        const int kx = k % 3;
        const vf2 o = off2[k];
        vf2 f;
        f.x = floorf(o.x);
        f.y = floorf(o.y);
        const vf2 w  = o - f;
        const vf2 cw = splat2(1.f) - w;

        int iy = (int)f.x + (ho + ky + PAD);
        int ix = (int)f.y + (wo + kx + PAD);
        iy = min(max(iy, 0), HP - 2);
        ix = min(max(ix, 0), WP - 2);

        const uint2* base = xtb + iy * WP + ix;
        const uint2 q00 = base[0];
        const uint2 q01 = base[1];
        const uint2 q10 = base[WP];
        const uint2 q11 = base[WP + 1];

        const float w00 = cw.x * cw.y;
        const float w01 = cw.x * w.y;
        const float w10 = w.x * cw.y;
        const float w11 = w.x * w.y;

        vf2 c00, c01, c10, c11;
        c00.x = bf_lo(q00.x); c00.y = bf_hi(q00.x);
        c01.x = bf_lo(q01.x); c01.y = bf_hi(q01.x);
        c10.x = bf_lo(q10.x); c10.y = bf_hi(q10.x);
        c11.x = bf_lo(q11.x); c11.y = bf_hi(q11.x);
        vf2 s01 = c00 * splat2(w00);
        s01 = __builtin_elementwise_fma(c01, splat2(w01), s01);
        s01 = __builtin_elementwise_fma(c10, splat2(w10), s01);
        s01 = __builtin_elementwise_fma(c11, splat2(w11), s01);

        float s2 = bf_lo(q00.y) * w00;
        s2 = fmaf(bf_lo(q01.y), w01, s2);
        s2 = fmaf(bf_lo(q10.y), w10, s2);
        s2 = fmaf(bf_lo(q11.y), w11, s2);

        acc01 = __builtin_elementwise_fma(pk_dw[0 * 9 + k], splat2(s01.x), acc01);
        acc01 = __builtin_elementwise_fma(pk_dw[1 * 9 + k], splat2(s01.y), acc01);
        acc01 = __builtin_elementwise_fma(pk_dw[2 * 9 + k], splat2(s2),    acc01);
        acc2 = fmaf(dw2[0 * 9 + k], s01.x, acc2);
        acc2 = fmaf(dw2[1 * 9 + k], s01.y, acc2);
        acc2 = fmaf(dw2[2 * 9 + k], s2,    acc2);
    }

    const int obase = b * (OOUT * HO * WO) + ho * WO + wo;
    __builtin_nontemporal_store(acc01.x, out + obase);
    __builtin_nontemporal_store(acc01.y, out + obase + HO * WO);
    __builtin_nontemporal_store(acc2,    out + obase + 2 * HO * WO);
}

// ---------------------------------------------------------------------------
// Fallback B (tiny ws): round-2 fused kernel (~176 us), no workspace.
__global__ __launch_bounds__(256)
void deform_fused_kernel(const float* __restrict__ x,
                         const float* __restrict__ conv_w,
                         const float* __restrict__ conv_b,
                         const float* __restrict__ dcn_w,
                         const float* __restrict__ dcn_b,
                         float* __restrict__ out)
{
    __shared__ float s_cw[OFFC * 27];
    __shared__ float s_cb[OFFC];
    __shared__ float s_dw[OOUT * 27];
    __shared__ float s_db[OOUT];

    const int t = threadIdx.x;
    for (int i = t; i < OFFC * 27; i += 256) s_cw[i] = conv_w[i];
    if (t < OFFC)      s_cb[t] = conv_b[t];
    if (t < OOUT * 27) s_dw[t] = dcn_w[t];
    if (t < OOUT)      s_db[t] = dcn_b[t];
    __syncthreads();

    const int total = BATCH * HO * WO;
    const int gid = blockIdx.x * 256 + t;
    if (gid >= total) return;

    const int wo  = gid % WO;
    const int tmp = gid / WO;
    const int ho  = tmp % HO;
    const int b   = tmp / HO;

    const float* xb = x + b * (CIN * HW);

    float xp[CIN][3][3];
    #pragma unroll
    for (int c = 0; c < CIN; ++c) {
        const float* xc = xb + c * HW + ho * W + wo;
        #pragma unroll
        for (int i = 0; i < 3; ++i)
            #pragma unroll
            for (int j = 0; j < 3; ++j)
                xp[c][i][j] = xc[i * W + j];
    }

    float off[OFFC];
    #pragma unroll
    for (int o = 0; o < OFFC; ++o) {
        float a = s_cb[o];
        const float* wv = &s_cw[o * 27];
        #pragma unroll
        for (int c = 0; c < CIN; ++c)
            #pragma unroll
            for (int i = 0; i < 3; ++i)
                #pragma unroll
                for (int j = 0; j < 3; ++j)
                    a = fmaf(wv[c * 9 + i * 3 + j], xp[c][i][j], a);
        off[o] = a;
    }

    float a0 = s_db[0], a1 = s_db[1], a2 = s_db[2];

    #pragma unroll
    for (int k = 0; k < KTAPS; ++k) {
        const int ky = k / 3;
        const int kx = k % 3;
        const float py = off[2 * k]     + (float)(ho + ky);
        const float px = off[2 * k + 1] + (float)(wo + kx);
        const float y0f = floorf(py);
        const float x0f = floorf(px);
        const float wy = py - y0f;
        const float wx = px - x0f;
        const int y0 = (int)y0f;
        const int x0 = (int)x0f;
        const int y1 = y0 + 1;
        const int x1 = x0 + 1;
        const bool vy0 = (unsigned)y0 < (unsigned)H;
        const bool vy1 = (unsigned)y1 < (unsigned)H;
        const bool vx0 = (unsigned)x0 < (unsigned)W;
        const bool vx1 = (unsigned)x1 < (unsigned)W;
        const int cy0 = min(max(y0, 0), H - 1);
        const int cy1 = min(max(y1, 0), H - 1);
        const int cx0 = min(max(x0, 0), W - 1);
        const int cx1 = min(max(x1, 0), W - 1);
        const float w00 = (vy0 && vx0) ? (1.f - wy) * (1.f - wx) : 0.f;
        const float w01 = (vy0 && vx1) ? (1.f - wy) * wx         : 0.f;
        const float w10 = (vy1 && vx0) ? wy * (1.f - wx)         : 0.f;
        const float w11 = (vy1 && vx1) ? wy * wx                 : 0.f;
        const int i00 = cy0 * W + cx0;
        const int i01 = cy0 * W + cx1;
        const int i10 = cy1 * W + cx0;
        const int i11 = cy1 * W + cx1;
        #pragma unroll
        for (int c = 0; c < CIN; ++c) {
            const float* xc = xb + c * HW;
            float s = xc[i00] * w00;
            s = fmaf(xc[i01], w01, s);
            s = fmaf(xc[i10], w10, s);
            s = fmaf(xc[i11], w11, s);
            a0 = fmaf(s_dw[0 * 27 + c * 9 + k], s, a0);
            a1 = fmaf(s_dw[1 * 27 + c * 9 + k], s, a1);
            a2 = fmaf(s_dw[2 * 27 + c * 9 + k], s, a2);
        }
    }

    const int obase = b * (OOUT * HO * WO) + ho * WO + wo;
    __builtin_nontemporal_store(a0, out + obase);
    __builtin_nontemporal_store(a1, out + obase + HO * WO);
    __builtin_nontemporal_store(a2, out + obase + 2 * HO * WO);
}

extern "C" void kernel_launch(void* const* d_in, const int* in_sizes, int n_in,
                              void* d_out, int out_size, void* d_ws, size_t ws_size,
                              hipStream_t stream) {
    const float* x      = (const float*)d_in[0];
    const float* conv_w = (const float*)d_in[1];
    const float* conv_b = (const float*)d_in[2];
    const float* dcn_w  = (const float*)d_in[3];
    const float* dcn_b  = (const float*)d_in[4];
    float* out = (float*)d_out;

    const int total = BATCH * HO * WO;
    const size_t cells_bytes = (size_t)BATCH * HP * WP * sizeof(uint4);  // 38.5 MB
    const size_t need_cells  = cells_bytes + WPK_FLOATS * sizeof(float);
    const size_t xt_bytes    = (size_t)BATCH * HP * WP * sizeof(uint2);  // 19.3 MB
    const size_t need_bf     = xt_bytes + WPK_FLOATS * sizeof(float);

    if (ws_size >= need_cells) {
        uint4* cells = (uint4*)d_ws;
        float* wpk = (float*)((char*)d_ws + cells_bytes);
        prep_weights_kernel<<<1, 256, 0, stream>>>(conv_w, conv_b, dcn_w, dcn_b, wpk);
        const int nc = BATCH * HP * WP;
        chw_to_cells_kernel<<<(nc + 255) / 256, 256, 0, stream>>>(x, cells);
        dim3 grid((HO * WO + 255) / 256, BATCH, 1);
        deform_cells_kernel<<<grid, 256, 0, stream>>>(x, cells, wpk, out);
    } else if (ws_size >= need_bf) {
        uint2* xt = (uint2*)d_ws;
        float* wpk = (float*)((char*)d_ws + xt_bytes);
        prep_weights_kernel<<<1, 256, 0, stream>>>(conv_w, conv_b, dcn_w, dcn_b, wpk);
        const int nc = BATCH * HP * WP;
        chw_to_bf16hwc_kernel<<<(nc + 255) / 256, 256, 0, stream>>>(x, xt);
        deform_bf16_kernel<<<(total + 255) / 256, 256, 0, stream>>>(x, xt, wpk, out);
    } else {
        deform_fused_kernel<<<(total + 255) / 256, 256, 0, stream>>>(
            x, conv_w, conv_b, dcn_w, dcn_b, out);
    }
}